// Round 5
// baseline (181.212 us; speedup 1.0000x reference)
//
#include <hip/hip_runtime.h>
#include <math.h>

#define PLANES   8192   // 16 batches * 512 channels
#define PLANE_SZ 4096   // 64*64
#define CHANS    512
#define NBLK     512    // 2 blocks/CU * 256 CUs -> co-resident by launch_bounds
#define PPB      8      // planes per block per phase
#define NPHASE   2      // 512*8*2 = 8192 planes; phase = 8 whole batches
#define NGRP     8
#define GRP_SZ   (NBLK / NGRP)

typedef float f32x4 __attribute__((ext_vector_type(4)));

// ---------------------------------------------------------------------------
// Two-level generation barrier (regular launch, graph-capture safe).
// cnt[NGRP] group counters (64B apart), root counter, gen counter.
// All state zeroed by hipMemsetAsync at the start of every kernel_launch.
// ---------------------------------------------------------------------------
__device__ __forceinline__ void grid_barrier(unsigned* cnt, unsigned* root,
                                             unsigned* gen, int gid)
{
    __syncthreads();
    if (threadIdx.x == 0) {
        unsigned g = __hip_atomic_load(gen, __ATOMIC_RELAXED, __HIP_MEMORY_SCOPE_AGENT);
        __threadfence();   // release gp writes to device scope
        unsigned a = __hip_atomic_fetch_add(&cnt[gid * 16], 1u,
                                            __ATOMIC_ACQ_REL, __HIP_MEMORY_SCOPE_AGENT);
        if (a == GRP_SZ - 1) {
            __hip_atomic_store(&cnt[gid * 16], 0u, __ATOMIC_RELAXED, __HIP_MEMORY_SCOPE_AGENT);
            unsigned r = __hip_atomic_fetch_add(root, 1u,
                                                __ATOMIC_ACQ_REL, __HIP_MEMORY_SCOPE_AGENT);
            if (r == NGRP - 1) {
                __hip_atomic_store(root, 0u, __ATOMIC_RELAXED, __HIP_MEMORY_SCOPE_AGENT);
                __hip_atomic_fetch_add(gen, 1u, __ATOMIC_RELEASE, __HIP_MEMORY_SCOPE_AGENT);
            } else {
                while (__hip_atomic_load(gen, __ATOMIC_ACQUIRE, __HIP_MEMORY_SCOPE_AGENT) == g)
                    __builtin_amdgcn_s_sleep(2);
            }
        } else {
            while (__hip_atomic_load(gen, __ATOMIC_ACQUIRE, __HIP_MEMORY_SCOPE_AGENT) == g)
                __builtin_amdgcn_s_sleep(2);
        }
        __threadfence();   // acquire side: subsequent gp reads see fresh data
    }
    __syncthreads();
}

// ---------------------------------------------------------------------------
// Single-pass persistent kernel. Per phase: load 8 planes into registers,
// means -> gp, grid barrier, gates from gp window, scale registers, NT-store.
// Input read from HBM exactly once.
// ---------------------------------------------------------------------------
__global__ __launch_bounds__(256, 2) void fused_kernel(
    const float* __restrict__ x1, const float* __restrict__ x2,
    const float* __restrict__ x3, const float* __restrict__ x4,
    const float* __restrict__ conv_w, const float* __restrict__ conv_b,
    const float* __restrict__ lin_w,  const float* __restrict__ lin_b,
    float* __restrict__ gp, unsigned* __restrict__ bar,
    float* __restrict__ out)
{
    const int tid = threadIdx.x;
    const int blk = blockIdx.x;
    const int gid = blk >> 6;              // barrier group
    unsigned* cnt  = bar;                  // NGRP*16 uints
    unsigned* root = bar + NGRP * 16;      // 16 uints apart
    unsigned* gen  = bar + NGRP * 16 + 16;

    __shared__ float gwin[PPB + 64];       // gp window [c1-32 .. c1+PPB+31]
    __shared__ float wsum[PPB][4];
    __shared__ float gates[PPB];

    for (int g = 0; g < NPHASE; ++g) {
        const int pA = g * (NBLK * PPB) + blk * PPB;   // first plane (mult of 8)
        const int b  = pA >> 9;
        const int c1 = pA & (CHANS - 1);
        const int xi = c1 >> 7;            // 8 | 128 -> all 8 planes same source
        const float* src = (xi == 0) ? x1 : (xi == 1) ? x2 : (xi == 2) ? x3 : x4;
        const f32x4* p4 = (const f32x4*)(src + (size_t)(b * 128 + (c1 & 127)) * PLANE_SZ);

        // load 8 planes (128 KB) into registers
        f32x4 v[PPB][4];
        #pragma unroll
        for (int p = 0; p < PPB; ++p)
            #pragma unroll
            for (int j = 0; j < 4; ++j)
                v[p][j] = p4[p * 1024 + j * 256 + tid];

        // per-plane partial sums
        float s[PPB];
        #pragma unroll
        for (int p = 0; p < PPB; ++p) {
            f32x4 t = (v[p][0] + v[p][1]) + (v[p][2] + v[p][3]);
            s[p] = (t.x + t.y) + (t.z + t.w);
        }
        #pragma unroll
        for (int off = 32; off > 0; off >>= 1)
            #pragma unroll
            for (int p = 0; p < PPB; ++p)
                s[p] += __shfl_down(s[p], off, 64);
        if ((tid & 63) == 0)
            #pragma unroll
            for (int p = 0; p < PPB; ++p)
                wsum[p][tid >> 6] = s[p];
        __syncthreads();
        if (tid < PPB)
            gp[pA + tid] = ((wsum[tid][0] + wsum[tid][1]) +
                            (wsum[tid][2] + wsum[tid][3])) * (1.0f / PLANE_SZ);

        grid_barrier(cnt, root, gen, gid);   // all means of this phase visible

        // stage gp[b, c1-32 .. c1+39] (zero-pad outside [0,512))
        if (tid < PPB + 64) {
            int idx = c1 - 32 + tid;
            gwin[tid] = (idx >= 0 && idx < CHANS) ? gp[b * CHANS + idx] : 0.f;
        }
        __syncthreads();

        // gates for channels c1..c1+7 (taps at d*(k-4), d = 1,2,4,8)
        if (tid < PPB) {
            float lin = lin_b[0];
            #pragma unroll
            for (int i = 0; i < 4; ++i) {
                const int d = 1 << i;
                float acc = conv_b[i];
                #pragma unroll
                for (int k = 0; k < 9; ++k)
                    acc += conv_w[i * 9 + k] * gwin[32 + tid + d * (k - 4)];
                lin += lin_w[i] * fmaxf(acc, 0.f);
            }
            gates[tid] = 1.0f / (1.0f + expf(-lin));
        }
        __syncthreads();

        // scale retained registers, stream out non-temporally
        f32x4* o4 = (f32x4*)(out + (size_t)pA * PLANE_SZ);
        #pragma unroll
        for (int p = 0; p < PPB; ++p) {
            const float gv = gates[p];
            #pragma unroll
            for (int j = 0; j < 4; ++j) {
                f32x4 t = v[p][j] * gv;
                __builtin_nontemporal_store(t, &o4[p * 1024 + j * 256 + tid]);
            }
        }
    }
}

extern "C" void kernel_launch(void* const* d_in, const int* in_sizes, int n_in,
                              void* d_out, int out_size, void* d_ws, size_t ws_size,
                              hipStream_t stream) {
    const float* x1     = (const float*)d_in[0];
    const float* x2     = (const float*)d_in[1];
    const float* x3     = (const float*)d_in[2];
    const float* x4     = (const float*)d_in[3];
    const float* conv_w = (const float*)d_in[4];
    const float* conv_b = (const float*)d_in[5];
    const float* lin_w  = (const float*)d_in[6];
    const float* lin_b  = (const float*)d_in[7];
    float* out = (float*)d_out;

    float*    gp  = (float*)d_ws;                         // PLANES floats
    unsigned* bar = (unsigned*)((char*)d_ws + PLANES * sizeof(float));

    // barrier state must be zero at the start of EVERY call (ws is poisoned)
    hipMemsetAsync(bar, 0, 1024, stream);

    fused_kernel<<<NBLK, 256, 0, stream>>>(x1, x2, x3, x4,
                                           conv_w, conv_b, lin_w, lin_b,
                                           gp, bar, out);
}